// Round 5
// baseline (213.339 us; speedup 1.0000x reference)
//
#include <hip/hip_runtime.h>

// SpatialTransformer: 3D trilinear warp, zeros padding.
// src [B,C,D,H,W] f32 = [2,2,128,160,128]; flow [B,3,D,H,W]; out [B,C,D,H,W].
//
// R13: PURE GATHER — no LDS, no barriers. Post-mortems R8-R12: four
// structurally different staged kernels all land 68-84us with nothing
// saturated (VALU 25-47%, HBM 23-37%, occupancy 50-73%); R12's clean
// software pipeline made it WORSE. The invariant cost is the staging
// structure itself: stage -> vmcnt(0)+barrier -> conflicted ds_read_b64
// random gather (constant 4.7M conflict cycles every round).
// This is learn_hip m169 / Common-mistake #7: the LDS tile is a software
// cache for data the HW caches already serve. A wave (= half an x-row)
// gathers within a ~4-plane x 3-row x 70-col window: L1-resident; y/z
// halo reuse across blocks: L2/L3-resident (problem = 147 MB < 256 MB L3).
//  - Per thread: 3 coalesced flow loads -> coords/weights (once per
//    channel-PAIR, channel fusion kept from R9) -> 16 independent scalar
//    gather loads (4 corner rows x 2 x-corners x 2 channels) -> 2 stores.
//  - Scalar gathers are REQUIRED: xp has arbitrary parity; dwordx2 needs
//    8B alignment. This is exactly the verified fallback path, applied
//    everywhere -> correctness inherited.
//  - No LDS, VGPR ~55 under loose (256,4)=128 cap -> no spill risk,
//    occupancy -> waves-limited (32/CU). 16-deep per-thread MLP x 32
//    waves/CU hides L1/L2 gather latency.
//  - Block = 256 thr = x:128 x y:2 rows (wave = half x-row -> gather
//    lines shared across lanes). Grid 1 x 80 x 256 = 20480 blocks.

#define B_ 2
#define C_ 2
#define D_ 128
#define H_ 160
#define W_ 128
constexpr int S_ = D_ * H_ * W_;

#define NTHREADS 256

__device__ __forceinline__ float pair_val(const float* p, bool hi0, bool lo1,
                                          float wx0, float wx1) {
    const float v0 = hi0 ? p[1] : p[0];
    const float v1 = lo1 ? p[0] : p[1];
    return wx0 * v0 + wx1 * v1;
}

__global__ __launch_bounds__(NTHREADS, 4) void warp3d_gather(
    const float* __restrict__ src,
    const float* __restrict__ flow,
    float* __restrict__ out)
{
    const int tid = threadIdx.x;
    const int x = tid & (W_ - 1);                  // 0..127
    const int y = blockIdx.y * 2 + (tid >> 7);     // 2 rows per block
    const int bz = blockIdx.z;
    const int z = bz & (D_ - 1);
    const int b = bz >> 7;

    const float* fb = flow + (long long)b * 3 * S_;
    const float* s0 = src + (long long)b * C_ * S_;   // ch0; ch1 = s0 + S_
    float* o0       = out + (long long)b * C_ * S_;

    const int s = (z * H_ + y) * W_ + x;

    // coalesced flow loads (lane-contiguous)
    const float fz = fb[s], fy = fb[S_ + s], fx = fb[2 * S_ + s];

    const float iz = (float)z + fz;
    const float iy = (float)y + fy;
    const float ix = (float)x + fx;

    const float zf = floorf(iz), yf = floorf(iy), xf = floorf(ix);
    const float tz = iz - zf, ty = iy - yf, tx = ix - xf;
    const int z0 = (int)zf, y0 = (int)yf, x0 = (int)xf;

    const int zc0 = min(max(z0, 0), D_ - 1), zc1 = min(max(z0 + 1, 0), D_ - 1);
    const int yc0 = min(max(y0, 0), H_ - 1), yc1 = min(max(y0 + 1, 0), H_ - 1);
    const int xp  = min(max(x0, 0), W_ - 2);

    const float wz0 = ((unsigned)z0       < (unsigned)D_) ? (1.f - tz) : 0.f;
    const float wz1 = ((unsigned)(z0 + 1) < (unsigned)D_) ? tz         : 0.f;
    const float wy0 = ((unsigned)y0       < (unsigned)H_) ? (1.f - ty) : 0.f;
    const float wy1 = ((unsigned)(y0 + 1) < (unsigned)H_) ? ty         : 0.f;
    const float wx0 = ((unsigned)x0       < (unsigned)W_) ? (1.f - tx) : 0.f;
    const float wx1 = ((unsigned)(x0 + 1) < (unsigned)W_) ? tx         : 0.f;
    const bool hi0 = x0 > xp;   // x0 == W-1
    const bool lo1 = x0 < xp;   // x0 == -1

    // 4 corner rows; 2 x-corners x 2 channels each = 16 scalar gathers,
    // all independent -> deep MLP, served by L1/L2/L3.
    const int l00 = (zc0 * H_ + yc0) * W_ + xp;
    const int l01 = (zc0 * H_ + yc1) * W_ + xp;
    const int l10 = (zc1 * H_ + yc0) * W_ + xp;
    const int l11 = (zc1 * H_ + yc1) * W_ + xp;

    const float q00 = pair_val(s0 + l00, hi0, lo1, wx0, wx1);
    const float q01 = pair_val(s0 + l01, hi0, lo1, wx0, wx1);
    const float q10 = pair_val(s0 + l10, hi0, lo1, wx0, wx1);
    const float q11 = pair_val(s0 + l11, hi0, lo1, wx0, wx1);
    const float r00 = pair_val(s0 + S_ + l00, hi0, lo1, wx0, wx1);
    const float r01 = pair_val(s0 + S_ + l01, hi0, lo1, wx0, wx1);
    const float r10 = pair_val(s0 + S_ + l10, hi0, lo1, wx0, wx1);
    const float r11 = pair_val(s0 + S_ + l11, hi0, lo1, wx0, wx1);

    const float acc0 = wz0 * (wy0 * q00 + wy1 * q01) + wz1 * (wy0 * q10 + wy1 * q11);
    const float acc1 = wz0 * (wy0 * r00 + wy1 * r01) + wz1 * (wy0 * r10 + wy1 * r11);

    o0[s]      = acc0;
    o0[S_ + s] = acc1;
}

extern "C" void kernel_launch(void* const* d_in, const int* in_sizes, int n_in,
                              void* d_out, int out_size, void* d_ws, size_t ws_size,
                              hipStream_t stream) {
    const float* src  = (const float*)d_in[0];
    const float* flow = (const float*)d_in[1];
    float* out = (float*)d_out;

    // grid: y 80 (2-row groups), z = 128 z x 2 batches -> 20480 blocks
    dim3 grid(1, H_ / 2, D_ * B_);
    warp3d_gather<<<grid, NTHREADS, 0, stream>>>(src, flow, out);
}

// Round 6
// 201.270 us; speedup vs baseline: 1.0600x; 1.0600x over previous
//
#include <hip/hip_runtime.h>

// SpatialTransformer: 3D trilinear warp, zeros padding.
// src [B,C,D,H,W] f32 = [2,2,128,160,128]; flow [B,3,D,H,W]; out [B,C,D,H,W].
//
// R14: R13 + FORCED MLP. R13 post-mortem: pure gather ran 117us with ALL
// pipes idle (VALU 14%, HBM 16%, conflicts 0, occ 81%) and VGPR_Count=28.
// 28 regs cannot hold 16 in-flight gathers -> compiler batched the loads
// ~4 deep-dependent groups, each thread serially eating ~4x L1/L2 latency.
// FETCH stayed 109 MB (lowest yet) -> caches DO absorb the gather; the
// problem is load serialization, not traffic.
// This round changes ONE thing (A/B discipline): all 16 corner loads are
// hoisted into named scalars in a single load phase before any blend, so
// every gather is issued before the first s_waitcnt. Loose (256,4) cap =
// 128 VGPR; need ~60-80.
//  - Geometry identical to R13: block 256 = x:128 x y:2, grid 1x80x256,
//    no LDS, no barriers, channel-fused (weights computed once per pair).
// Prediction: VGPR -> 56-88. If dur -> 45-60us, serialization confirmed,
// continue gather path. If dur >= 95us, divergent-address TA wall
// confirmed -> revert to R8 structure + LDS conflict swizzle.

#define B_ 2
#define C_ 2
#define D_ 128
#define H_ 160
#define W_ 128
constexpr int S_ = D_ * H_ * W_;

#define NTHREADS 256

__global__ __launch_bounds__(NTHREADS, 4) void warp3d_gather(
    const float* __restrict__ src,
    const float* __restrict__ flow,
    float* __restrict__ out)
{
    const int tid = threadIdx.x;
    const int x = tid & (W_ - 1);                  // 0..127
    const int y = blockIdx.y * 2 + (tid >> 7);     // 2 rows per block
    const int bz = blockIdx.z;
    const int z = bz & (D_ - 1);
    const int b = bz >> 7;

    const float* fb = flow + (long long)b * 3 * S_;
    const float* s0 = src + (long long)b * C_ * S_;   // ch0; ch1 = s0 + S_
    float* o0       = out + (long long)b * C_ * S_;

    const int s = (z * H_ + y) * W_ + x;

    // coalesced flow loads (lane-contiguous)
    const float fz = fb[s], fy = fb[S_ + s], fx = fb[2 * S_ + s];

    const float iz = (float)z + fz;
    const float iy = (float)y + fy;
    const float ix = (float)x + fx;

    const float zf = floorf(iz), yf = floorf(iy), xf = floorf(ix);
    const float tz = iz - zf, ty = iy - yf, tx = ix - xf;
    const int z0 = (int)zf, y0 = (int)yf, x0 = (int)xf;

    const int zc0 = min(max(z0, 0), D_ - 1), zc1 = min(max(z0 + 1, 0), D_ - 1);
    const int yc0 = min(max(y0, 0), H_ - 1), yc1 = min(max(y0 + 1, 0), H_ - 1);
    const int xp  = min(max(x0, 0), W_ - 2);

    const float wz0 = ((unsigned)z0       < (unsigned)D_) ? (1.f - tz) : 0.f;
    const float wz1 = ((unsigned)(z0 + 1) < (unsigned)D_) ? tz         : 0.f;
    const float wy0 = ((unsigned)y0       < (unsigned)H_) ? (1.f - ty) : 0.f;
    const float wy1 = ((unsigned)(y0 + 1) < (unsigned)H_) ? ty         : 0.f;
    const float wx0 = ((unsigned)x0       < (unsigned)W_) ? (1.f - tx) : 0.f;
    const float wx1 = ((unsigned)(x0 + 1) < (unsigned)W_) ? tx         : 0.f;
    const bool hi0 = x0 > xp;   // x0 == W-1
    const bool lo1 = x0 < xp;   // x0 == -1

    // ---- address phase: 4 corner rows ----
    const int l00 = (zc0 * H_ + yc0) * W_ + xp;
    const int l01 = (zc0 * H_ + yc1) * W_ + xp;
    const int l10 = (zc1 * H_ + yc0) * W_ + xp;
    const int l11 = (zc1 * H_ + yc1) * W_ + xp;

    // ---- LOAD PHASE: all 16 gathers issued before ANY consumption ----
    // (named scalars -> no reg recycling -> all loads in flight at once)
    const float a00 = s0[l00],      b00 = s0[l00 + 1];
    const float a01 = s0[l01],      b01 = s0[l01 + 1];
    const float a10 = s0[l10],      b10 = s0[l10 + 1];
    const float a11 = s0[l11],      b11 = s0[l11 + 1];
    const float c00 = s0[S_ + l00], d00 = s0[S_ + l00 + 1];
    const float c01 = s0[S_ + l01], d01 = s0[S_ + l01 + 1];
    const float c10 = s0[S_ + l10], d10 = s0[S_ + l10 + 1];
    const float c11 = s0[S_ + l11], d11 = s0[S_ + l11 + 1];

    // ---- blend phase ----
    const float q00 = wx0 * (hi0 ? b00 : a00) + wx1 * (lo1 ? a00 : b00);
    const float q01 = wx0 * (hi0 ? b01 : a01) + wx1 * (lo1 ? a01 : b01);
    const float q10 = wx0 * (hi0 ? b10 : a10) + wx1 * (lo1 ? a10 : b10);
    const float q11 = wx0 * (hi0 ? b11 : a11) + wx1 * (lo1 ? a11 : b11);
    const float r00 = wx0 * (hi0 ? d00 : c00) + wx1 * (lo1 ? c00 : d00);
    const float r01 = wx0 * (hi0 ? d01 : c01) + wx1 * (lo1 ? c01 : d01);
    const float r10 = wx0 * (hi0 ? d10 : c10) + wx1 * (lo1 ? c10 : d10);
    const float r11 = wx0 * (hi0 ? d11 : c11) + wx1 * (lo1 ? c11 : d11);

    const float acc0 = wz0 * (wy0 * q00 + wy1 * q01) + wz1 * (wy0 * q10 + wy1 * q11);
    const float acc1 = wz0 * (wy0 * r00 + wy1 * r01) + wz1 * (wy0 * r10 + wy1 * r11);

    o0[s]      = acc0;
    o0[S_ + s] = acc1;
}

extern "C" void kernel_launch(void* const* d_in, const int* in_sizes, int n_in,
                              void* d_out, int out_size, void* d_ws, size_t ws_size,
                              hipStream_t stream) {
    const float* src  = (const float*)d_in[0];
    const float* flow = (const float*)d_in[1];
    float* out = (float*)d_out;

    // grid: y 80 (2-row groups), z = 128 z x 2 batches -> 20480 blocks
    dim3 grid(1, H_ / 2, D_ * B_);
    warp3d_gather<<<grid, NTHREADS, 0, stream>>>(src, flow, out);
}

// Round 7
// 162.196 us; speedup vs baseline: 1.3153x; 1.2409x over previous
//
#include <hip/hip_runtime.h>

// SpatialTransformer: 3D trilinear warp, zeros padding.
// src [B,C,D,H,W] f32 = [2,2,128,160,128]; flow [B,3,D,H,W]; out [B,C,D,H,W].
//
// R15: X-QUAD THREADS + PADDED LDS. Cross-round evidence: per-thread ILP
// correlates with speed (R8 4vox=68us, R9 2pair=70, R10 1pair=72, R12
// 1pair+barriers=84); R13/R14 showed the compiler SERIALIZES independent
// scalar gathers (VGPR pinned at 20-28) - source order doesn't control
// scheduling. So make the wide ops STRUCTURAL:
//  - Each thread owns 4 consecutive-x voxel-pairs: flow = 3 x dwordx4
//    loads (was 12 scalar), out = 2 x dwordx4 stores (was 8). A dwordx4
//    arrives with ONE latency - un-serializable. 4 independent gather
//    chains per thread.
//  - LDS pad: interleaved row 40 -> 41 pairs. Old stride 8 mod 16
//    bank-pairs -> y,y+2 rows collide (8-way clusters, the constant 4.7M
//    conflict cycles). Stride 41 = 9 mod 16: 8 y-rows hit shifts
//    {0,9,2,11,4,13,6,15}, all distinct -> ~2-way (free, m136).
//  - Staging: float4 per channel per quad-chunk, pure register repack.
//  - LDS 10x14x41x2x4B = 44.8KB+pad = 45.9KB -> 3 blocks x 4 waves = 12
//    waves/CU. Accepted: R10 falsified the occupancy lever; betting on MLP.
//  - launch_bounds(256,4) = 128 VGPR cap, need ~90 -> no spill risk.
// Fallback (outside halo window): ~0.3% of lanes, exact global gather x2ch.

#define B_ 2
#define C_ 2
#define D_ 128
#define H_ 160
#define W_ 128
constexpr int S_ = D_ * H_ * W_;

#define ZT 4
#define YT 8
#define XT 32
#define RZ 3
#define RY 3
#define RX 4
#define CZ (ZT + 2 * RZ)   // 10
#define CY (YT + 2 * RY)   // 14
#define CX (XT + 2 * RX)   // 40 x-positions (pairs) per row
#define PADP 41            // padded row stride in pairs (9 mod 16: conflict-free)
#define NTHREADS 256
#define NQCHUNK (CZ * CY * (CX / 4))   // 1400 quad-chunks (4 x-positions each)

// Compute one voxel-pair (both channels) at global (x,y,z) with flow (fz,fy,fx).
// tile: interleaved {c0,c1} pairs, row stride PADP pairs. Returns {ch0, ch1}.
__device__ __forceinline__ float2 compute_pair(
    int x, int y, int z, float fz, float fy, float fx,
    int zb, int yb, int xb,
    int zlo, int zhi, int ylo, int yhi, int xlo, int xhi,
    const float* __restrict__ tile, const float* __restrict__ s0)
{
    const float iz = (float)z + fz;
    const float iy = (float)y + fy;
    const float ix = (float)x + fx;

    const float zf = floorf(iz), yf = floorf(iy), xf = floorf(ix);
    const float tz = iz - zf, ty = iy - yf, tx = ix - xf;
    const int z0 = (int)zf, y0 = (int)yf, x0 = (int)xf;

    const int zc0 = min(max(z0, 0), D_ - 1), zc1 = min(max(z0 + 1, 0), D_ - 1);
    const int yc0 = min(max(y0, 0), H_ - 1), yc1 = min(max(y0 + 1, 0), H_ - 1);
    const int xp  = min(max(x0, 0), W_ - 2);

    const float wz0 = ((unsigned)z0       < (unsigned)D_) ? (1.f - tz) : 0.f;
    const float wz1 = ((unsigned)(z0 + 1) < (unsigned)D_) ? tz         : 0.f;
    const float wy0 = ((unsigned)y0       < (unsigned)H_) ? (1.f - ty) : 0.f;
    const float wy1 = ((unsigned)(y0 + 1) < (unsigned)H_) ? ty         : 0.f;
    const float wx0 = ((unsigned)x0       < (unsigned)W_) ? (1.f - tx) : 0.f;
    const float wx1 = ((unsigned)(x0 + 1) < (unsigned)W_) ? tx         : 0.f;
    const bool hi0 = x0 > xp;   // x0 == W-1
    const bool lo1 = x0 < xp;   // x0 == -1

    const bool fast = (zc0 >= zlo) & (zc1 < zhi) &
                      (yc0 >= ylo) & (yc1 < yhi) &
                      (xp >= xlo) & (xp + 1 < xhi);

    float acc0, acc1;
    if (fast) {
        const int izl0 = zc0 - (zb - RZ), izl1 = zc1 - (zb - RZ);
        const int iyl0 = yc0 - (yb - RY), iyl1 = yc1 - (yb - RY);
        const int ixl  = xp - (xb - RX);
        const int o00 = ((izl0 * CY + iyl0) * PADP + ixl) * 2;
        const int o01 = ((izl0 * CY + iyl1) * PADP + ixl) * 2;
        const int o10 = ((izl1 * CY + iyl0) * PADP + ixl) * 2;
        const int o11 = ((izl1 * CY + iyl1) * PADP + ixl) * 2;
        const float2 a00 = *(const float2*)&tile[o00], b00 = *(const float2*)&tile[o00 + 2];
        const float2 a01 = *(const float2*)&tile[o01], b01 = *(const float2*)&tile[o01 + 2];
        const float2 a10 = *(const float2*)&tile[o10], b10 = *(const float2*)&tile[o10 + 2];
        const float2 a11 = *(const float2*)&tile[o11], b11 = *(const float2*)&tile[o11 + 2];
        const float q00 = wx0 * (hi0 ? b00.x : a00.x) + wx1 * (lo1 ? a00.x : b00.x);
        const float q01 = wx0 * (hi0 ? b01.x : a01.x) + wx1 * (lo1 ? a01.x : b01.x);
        const float q10 = wx0 * (hi0 ? b10.x : a10.x) + wx1 * (lo1 ? a10.x : b10.x);
        const float q11 = wx0 * (hi0 ? b11.x : a11.x) + wx1 * (lo1 ? a11.x : b11.x);
        const float r00 = wx0 * (hi0 ? b00.y : a00.y) + wx1 * (lo1 ? a00.y : b00.y);
        const float r01 = wx0 * (hi0 ? b01.y : a01.y) + wx1 * (lo1 ? a01.y : b01.y);
        const float r10 = wx0 * (hi0 ? b10.y : a10.y) + wx1 * (lo1 ? a10.y : b10.y);
        const float r11 = wx0 * (hi0 ? b11.y : a11.y) + wx1 * (lo1 ? a11.y : b11.y);
        acc0 = wz0 * (wy0 * q00 + wy1 * q01) + wz1 * (wy0 * q10 + wy1 * q11);
        acc1 = wz0 * (wy0 * r00 + wy1 * r01) + wz1 * (wy0 * r10 + wy1 * r11);
    } else {
        const int l00 = (zc0 * H_ + yc0) * W_ + xp;
        const int l01 = (zc0 * H_ + yc1) * W_ + xp;
        const int l10 = (zc1 * H_ + yc0) * W_ + xp;
        const int l11 = (zc1 * H_ + yc1) * W_ + xp;
        const float a00 = s0[l00],      b00 = s0[l00 + 1];
        const float a01 = s0[l01],      b01 = s0[l01 + 1];
        const float a10 = s0[l10],      b10 = s0[l10 + 1];
        const float a11 = s0[l11],      b11 = s0[l11 + 1];
        const float c00 = s0[S_ + l00], d00 = s0[S_ + l00 + 1];
        const float c01 = s0[S_ + l01], d01 = s0[S_ + l01 + 1];
        const float c10 = s0[S_ + l10], d10 = s0[S_ + l10 + 1];
        const float c11 = s0[S_ + l11], d11 = s0[S_ + l11 + 1];
        const float q00 = wx0 * (hi0 ? b00 : a00) + wx1 * (lo1 ? a00 : b00);
        const float q01 = wx0 * (hi0 ? b01 : a01) + wx1 * (lo1 ? a01 : b01);
        const float q10 = wx0 * (hi0 ? b10 : a10) + wx1 * (lo1 ? a10 : b10);
        const float q11 = wx0 * (hi0 ? b11 : a11) + wx1 * (lo1 ? a11 : b11);
        const float r00 = wx0 * (hi0 ? d00 : c00) + wx1 * (lo1 ? c00 : d00);
        const float r01 = wx0 * (hi0 ? d01 : c01) + wx1 * (lo1 ? c01 : d01);
        const float r10 = wx0 * (hi0 ? d10 : c10) + wx1 * (lo1 ? c10 : d10);
        const float r11 = wx0 * (hi0 ? d11 : c11) + wx1 * (lo1 ? c11 : d11);
        acc0 = wz0 * (wy0 * q00 + wy1 * q01) + wz1 * (wy0 * q10 + wy1 * q11);
        acc1 = wz0 * (wy0 * r00 + wy1 * r01) + wz1 * (wy0 * r10 + wy1 * r11);
    }
    return make_float2(acc0, acc1);
}

__global__ __launch_bounds__(NTHREADS, 4) void warp3d_tile(
    const float* __restrict__ src,
    const float* __restrict__ flow,
    float* __restrict__ out)
{
    __shared__ float tile[CZ * CY * PADP * 2];   // 11480 floats = 45.9 KB

    const int tid = threadIdx.x;
    const int xb = blockIdx.x * XT;
    const int yb = blockIdx.y * YT;
    const int bz = blockIdx.z;
    const int zb = (bz & 31) * ZT;         // 32 z-tiles
    const int b  = bz >> 5;                // batch

    const float* fb = flow + (long long)b * 3 * S_;
    const float* s0 = src + (long long)b * C_ * S_;   // ch0; ch1 = s0 + S_
    float* o0       = out + (long long)b * C_ * S_;

    // ---- stage src tile (+halo), both channels interleaved, quad chunks ----
#pragma unroll
    for (int j = 0; j < 6; ++j) {
        const int lin = j * NTHREADS + tid;
        if (lin < NQCHUNK) {
            const int row = lin / 10;              // rz*CY+ry, 0..139
            const int c   = lin - row * 10;        // x-quad 0..9
            const int rz = row / CY, ry = row - rz * CY;
            const int gz = zb - RZ + rz;
            const int gy = yb - RY + ry;
            const int gx = xb - RX + c * 4;        // multiple of 4
            if ((unsigned)gz < (unsigned)D_ && (unsigned)gy < (unsigned)H_ &&
                (unsigned)gx <= (unsigned)(W_ - 4)) {
                const int off = (gz * H_ + gy) * W_ + gx;
                const float4 va = *(const float4*)(s0 + off);        // ch0 x..x+3
                const float4 vb = *(const float4*)(s0 + S_ + off);   // ch1 x..x+3
                float* dst = &tile[(row * PADP + c * 4) * 2];
                *(float4*)(dst)     = make_float4(va.x, vb.x, va.y, vb.y);
                *(float4*)(dst + 4) = make_float4(va.z, vb.z, va.w, vb.w);
            }
        }
    }
    __syncthreads();

    // ---- compute: each thread owns an x-quad (4 voxel-pairs) ----
    const int xq = tid & 7;                // 8 x-quads across XT=32
    const int ly = (tid >> 3) & 7;         // 8 y
    const int lz = tid >> 6;               // 4 z
    const int x0g = xb + xq * 4;
    const int y = yb + ly, z = zb + lz;
    const int sbase = (z * H_ + y) * W_ + x0g;

    // one-latency wide flow loads for all 4 pairs
    const float4 fz4 = *(const float4*)(fb + sbase);
    const float4 fy4 = *(const float4*)(fb + S_ + sbase);
    const float4 fx4 = *(const float4*)(fb + 2 * S_ + sbase);

    const int zlo = max(0, zb - RZ), zhi = min(D_, zb + ZT + RZ);
    const int ylo = max(0, yb - RY), yhi = min(H_, yb + YT + RY);
    const int xlo = max(0, xb - RX), xhi = min(W_, xb + XT + RX);

    const float2 v0 = compute_pair(x0g + 0, y, z, fz4.x, fy4.x, fx4.x,
                                   zb, yb, xb, zlo, zhi, ylo, yhi, xlo, xhi, tile, s0);
    const float2 v1 = compute_pair(x0g + 1, y, z, fz4.y, fy4.y, fx4.y,
                                   zb, yb, xb, zlo, zhi, ylo, yhi, xlo, xhi, tile, s0);
    const float2 v2 = compute_pair(x0g + 2, y, z, fz4.z, fy4.z, fx4.z,
                                   zb, yb, xb, zlo, zhi, ylo, yhi, xlo, xhi, tile, s0);
    const float2 v3 = compute_pair(x0g + 3, y, z, fz4.w, fy4.w, fx4.w,
                                   zb, yb, xb, zlo, zhi, ylo, yhi, xlo, xhi, tile, s0);

    // one-latency wide stores, both channels
    *(float4*)(o0 + sbase)      = make_float4(v0.x, v1.x, v2.x, v3.x);
    *(float4*)(o0 + S_ + sbase) = make_float4(v0.y, v1.y, v2.y, v3.y);
}

extern "C" void kernel_launch(void* const* d_in, const int* in_sizes, int n_in,
                              void* d_out, int out_size, void* d_ws, size_t ws_size,
                              hipStream_t stream) {
    const float* src  = (const float*)d_in[0];
    const float* flow = (const float*)d_in[1];
    float* out = (float*)d_out;

    // grid: x 4, y 20, z = 32 z-tiles x B2 = 64 -> 5120 blocks
    dim3 grid(W_ / XT, H_ / YT, (D_ / ZT) * B_);
    warp3d_tile<<<grid, NTHREADS, 0, stream>>>(src, flow, out);
}

// Round 8
// 152.713 us; speedup vs baseline: 1.3970x; 1.0621x over previous
//
#include <hip/hip_runtime.h>

// SpatialTransformer: 3D trilinear warp, zeros padding.
// src [B,C,D,H,W] f32 = [2,2,128,160,128]; flow [B,3,D,H,W]; out [B,C,D,H,W].
//
// R16: FIRE-AND-FORGET STAGING. Seven structures pinned at 68-72us with no
// pipe >50%: latency-bound because VGPR-staged loads stall their wave at
// first register reuse (R13/R14: compiler throttles MLP to its reg budget).
// Little's law: 6.3 TB/s needs ~9.2 KB in-flight/CU; measured 2.3 TB/s ~
// 3.4 KB. Fix = __builtin_amdgcn_global_load_lds width-16 (m93->m97 +69%):
// staging becomes zero-VGPR vmcnt-tracked DMA; each wave issues ~8 chunk
// DMAs + 3 flow dwordx4 back-to-back, pays ONE drain at the barrier.
//  - Linear LDS dest required -> two separate channel planes (no
//    interleave); x-pair gather = 2 adjacent 4B reads -> compiler merges
//    to ds_read2_b32 (4B-aligned, handles odd xp). 8 LDS instr/pair as
//    before. Conflicts proven non-lever (R15 pad test).
//  - No per-lane predication allowed -> ALL staging addresses clamped
//    in-bounds (R12 trick): garbage lands only in halo cells the fast
//    path provably never reads (its corner window is global-bounds-
//    clamped and tile-window-tested).
//  - Geometry z8 y8 x32, 512 thr, 4 pairs/thread: LDS 2x14x14x40x4B =
//    61.25 KB -> 2 blocks x 8 waves = 16 waves/CU (R15: 12); staged/
//    compulsory src 5.47 -> 3.83; grid 4x20x32 = 2560 = 5 exact rounds.
//  - launch_bounds(512,4) = 128 VGPR cap, need ~70 -> no spill risk.
// Falsification pre-commit: if dur ~70 again with VGPR<90 (DMA verified),
// the staged-gather class is at its wall -> declare.

#define B_ 2
#define C_ 2
#define D_ 128
#define H_ 160
#define W_ 128
constexpr int S_ = D_ * H_ * W_;

#define ZT 8
#define YT 8
#define XT 32
#define RZ 3
#define RY 3
#define RX 4
#define CZ (ZT + 2 * RZ)   // 14
#define CY (YT + 2 * RY)   // 14
#define CX (XT + 2 * RX)   // 40
#define NTHREADS 512
#define PLANE (CZ * CY * CX)        // 7840 floats per channel plane
#define CHPP (PLANE / 4)            // 1960 16B chunks per plane
#define NCHUNK_TOT (2 * CHPP)       // 3920 chunks total

typedef const __attribute__((address_space(1))) unsigned int ga_u32;
typedef __attribute__((address_space(3))) unsigned int lds_u32;

__device__ __forceinline__ void gload16(const float* g, float* l) {
    // 16B global -> LDS DMA; dest = wave-uniform base + lane*16 (our lin
    // mapping is lane-contiguous); no VGPR destination, vmcnt-tracked.
    __builtin_amdgcn_global_load_lds((ga_u32*)g, (lds_u32*)l, 16, 0, 0);
}

// One voxel-pair (both channels). tile = 2 planes of [CZ][CY][CX].
__device__ __forceinline__ float2 compute_pair(
    int x, int y, int z, float fz, float fy, float fx,
    int zb, int yb, int xb,
    int zlo, int zhi, int ylo, int yhi, int xlo, int xhi,
    const float* __restrict__ tile, const float* __restrict__ s0)
{
    const float iz = (float)z + fz;
    const float iy = (float)y + fy;
    const float ix = (float)x + fx;

    const float zf = floorf(iz), yf = floorf(iy), xf = floorf(ix);
    const float tz = iz - zf, ty = iy - yf, tx = ix - xf;
    const int z0 = (int)zf, y0 = (int)yf, x0 = (int)xf;

    const int zc0 = min(max(z0, 0), D_ - 1), zc1 = min(max(z0 + 1, 0), D_ - 1);
    const int yc0 = min(max(y0, 0), H_ - 1), yc1 = min(max(y0 + 1, 0), H_ - 1);
    const int xp  = min(max(x0, 0), W_ - 2);

    const float wz0 = ((unsigned)z0       < (unsigned)D_) ? (1.f - tz) : 0.f;
    const float wz1 = ((unsigned)(z0 + 1) < (unsigned)D_) ? tz         : 0.f;
    const float wy0 = ((unsigned)y0       < (unsigned)H_) ? (1.f - ty) : 0.f;
    const float wy1 = ((unsigned)(y0 + 1) < (unsigned)H_) ? ty         : 0.f;
    const float wx0 = ((unsigned)x0       < (unsigned)W_) ? (1.f - tx) : 0.f;
    const float wx1 = ((unsigned)(x0 + 1) < (unsigned)W_) ? tx         : 0.f;
    const bool hi0 = x0 > xp;   // x0 == W-1
    const bool lo1 = x0 < xp;   // x0 == -1

    const bool fast = (zc0 >= zlo) & (zc1 < zhi) &
                      (yc0 >= ylo) & (yc1 < yhi) &
                      (xp >= xlo) & (xp + 1 < xhi);

    float acc0, acc1;
    if (fast) {
        const int izl0 = zc0 - (zb - RZ), izl1 = zc1 - (zb - RZ);
        const int iyl0 = yc0 - (yb - RY), iyl1 = yc1 - (yb - RY);
        const int ixl  = xp - (xb - RX);
        const int o00 = (izl0 * CY + iyl0) * CX + ixl;
        const int o01 = (izl0 * CY + iyl1) * CX + ixl;
        const int o10 = (izl1 * CY + iyl0) * CX + ixl;
        const int o11 = (izl1 * CY + iyl1) * CX + ixl;
        // 2 adjacent 4B reads per row per plane -> ds_read2_b32
        const float a00 = tile[o00],         b00 = tile[o00 + 1];
        const float a01 = tile[o01],         b01 = tile[o01 + 1];
        const float a10 = tile[o10],         b10 = tile[o10 + 1];
        const float a11 = tile[o11],         b11 = tile[o11 + 1];
        const float c00 = tile[PLANE + o00], d00 = tile[PLANE + o00 + 1];
        const float c01 = tile[PLANE + o01], d01 = tile[PLANE + o01 + 1];
        const float c10 = tile[PLANE + o10], d10 = tile[PLANE + o10 + 1];
        const float c11 = tile[PLANE + o11], d11 = tile[PLANE + o11 + 1];
        const float q00 = wx0 * (hi0 ? b00 : a00) + wx1 * (lo1 ? a00 : b00);
        const float q01 = wx0 * (hi0 ? b01 : a01) + wx1 * (lo1 ? a01 : b01);
        const float q10 = wx0 * (hi0 ? b10 : a10) + wx1 * (lo1 ? a10 : b10);
        const float q11 = wx0 * (hi0 ? b11 : a11) + wx1 * (lo1 ? a11 : b11);
        const float r00 = wx0 * (hi0 ? d00 : c00) + wx1 * (lo1 ? c00 : d00);
        const float r01 = wx0 * (hi0 ? d01 : c01) + wx1 * (lo1 ? c01 : d01);
        const float r10 = wx0 * (hi0 ? d10 : c10) + wx1 * (lo1 ? c10 : d10);
        const float r11 = wx0 * (hi0 ? d11 : c11) + wx1 * (lo1 ? c11 : d11);
        acc0 = wz0 * (wy0 * q00 + wy1 * q01) + wz1 * (wy0 * q10 + wy1 * q11);
        acc1 = wz0 * (wy0 * r00 + wy1 * r01) + wz1 * (wy0 * r10 + wy1 * r11);
    } else {
        const int l00 = (zc0 * H_ + yc0) * W_ + xp;
        const int l01 = (zc0 * H_ + yc1) * W_ + xp;
        const int l10 = (zc1 * H_ + yc0) * W_ + xp;
        const int l11 = (zc1 * H_ + yc1) * W_ + xp;
        const float a00 = s0[l00],      b00 = s0[l00 + 1];
        const float a01 = s0[l01],      b01 = s0[l01 + 1];
        const float a10 = s0[l10],      b10 = s0[l10 + 1];
        const float a11 = s0[l11],      b11 = s0[l11 + 1];
        const float c00 = s0[S_ + l00], d00 = s0[S_ + l00 + 1];
        const float c01 = s0[S_ + l01], d01 = s0[S_ + l01 + 1];
        const float c10 = s0[S_ + l10], d10 = s0[S_ + l10 + 1];
        const float c11 = s0[S_ + l11], d11 = s0[S_ + l11 + 1];
        const float q00 = wx0 * (hi0 ? b00 : a00) + wx1 * (lo1 ? a00 : b00);
        const float q01 = wx0 * (hi0 ? b01 : a01) + wx1 * (lo1 ? a01 : b01);
        const float q10 = wx0 * (hi0 ? b10 : a10) + wx1 * (lo1 ? a10 : b10);
        const float q11 = wx0 * (hi0 ? b11 : a11) + wx1 * (lo1 ? a11 : b11);
        const float r00 = wx0 * (hi0 ? d00 : c00) + wx1 * (lo1 ? c00 : d00);
        const float r01 = wx0 * (hi0 ? d01 : c01) + wx1 * (lo1 ? c01 : d01);
        const float r10 = wx0 * (hi0 ? d10 : c10) + wx1 * (lo1 ? c10 : d10);
        const float r11 = wx0 * (hi0 ? d11 : c11) + wx1 * (lo1 ? c11 : d11);
        acc0 = wz0 * (wy0 * q00 + wy1 * q01) + wz1 * (wy0 * q10 + wy1 * q11);
        acc1 = wz0 * (wy0 * r00 + wy1 * r01) + wz1 * (wy0 * r10 + wy1 * r11);
    }
    return make_float2(acc0, acc1);
}

__global__ __launch_bounds__(NTHREADS, 4) void warp3d_tile(
    const float* __restrict__ src,
    const float* __restrict__ flow,
    float* __restrict__ out)
{
    __shared__ float tile[2 * PLANE];   // 15680 floats = 61.25 KB

    const int tid = threadIdx.x;
    const int xb = blockIdx.x * XT;
    const int yb = blockIdx.y * YT;
    const int bz = blockIdx.z;
    const int zb = (bz & 15) * ZT;         // 16 z-tiles
    const int b  = bz >> 4;                // batch

    const float* fb = flow + (long long)b * 3 * S_;
    const float* s0 = src + (long long)b * C_ * S_;   // ch0; ch1 = s0 + S_
    float* o0       = out + (long long)b * C_ * S_;

    // ---- staging: 3920 x 16B DMA chunks, zero VGPR dest, all clamped ----
#pragma unroll
    for (int j = 0; j < 8; ++j) {
        const int lin = j * NTHREADS + tid;
        if (lin < NCHUNK_TOT) {                // folds away for j < 7
            const int pl  = (lin >= CHPP) ? 1 : 0;
            const int rem = lin - pl * CHPP;
            const int row = rem / 10;          // rz*CY+ry, 0..195
            const int cq  = rem - row * 10;    // x-quad 0..9
            const int rz = row / CY, ry = row - rz * CY;
            const int gz = min(max(zb - RZ + rz, 0), D_ - 1);
            const int gy = min(max(yb - RY + ry, 0), H_ - 1);
            const int gx = min(max(xb - RX + cq * 4, 0), W_ - 4);
            gload16(s0 + pl * S_ + (gz * H_ + gy) * W_ + gx, &tile[lin * 4]);
        }
    }

    // ---- flow dwordx4 x3 issued while staging DMAs are in flight ----
    const int xq = tid & 7;                // 8 x-quads
    const int ly = (tid >> 3) & 7;         // 8 y
    const int lz = tid >> 6;               // 8 z
    const int x0g = xb + xq * 4;
    const int y = yb + ly, z = zb + lz;
    const int sbase = (z * H_ + y) * W_ + x0g;
    const float4 fz4 = *(const float4*)(fb + sbase);
    const float4 fy4 = *(const float4*)(fb + S_ + sbase);
    const float4 fx4 = *(const float4*)(fb + 2 * S_ + sbase);

    __syncthreads();   // single vmcnt(0) drain covers DMAs + flow

    const int zlo = max(0, zb - RZ), zhi = min(D_, zb + ZT + RZ);
    const int ylo = max(0, yb - RY), yhi = min(H_, yb + YT + RY);
    const int xlo = max(0, xb - RX), xhi = min(W_, xb + XT + RX);

    const float2 v0 = compute_pair(x0g + 0, y, z, fz4.x, fy4.x, fx4.x,
                                   zb, yb, xb, zlo, zhi, ylo, yhi, xlo, xhi, tile, s0);
    const float2 v1 = compute_pair(x0g + 1, y, z, fz4.y, fy4.y, fx4.y,
                                   zb, yb, xb, zlo, zhi, ylo, yhi, xlo, xhi, tile, s0);
    const float2 v2 = compute_pair(x0g + 2, y, z, fz4.z, fy4.z, fx4.z,
                                   zb, yb, xb, zlo, zhi, ylo, yhi, xlo, xhi, tile, s0);
    const float2 v3 = compute_pair(x0g + 3, y, z, fz4.w, fy4.w, fx4.w,
                                   zb, yb, xb, zlo, zhi, ylo, yhi, xlo, xhi, tile, s0);

    *(float4*)(o0 + sbase)      = make_float4(v0.x, v1.x, v2.x, v3.x);
    *(float4*)(o0 + S_ + sbase) = make_float4(v0.y, v1.y, v2.y, v3.y);
}

extern "C" void kernel_launch(void* const* d_in, const int* in_sizes, int n_in,
                              void* d_out, int out_size, void* d_ws, size_t ws_size,
                              hipStream_t stream) {
    const float* src  = (const float*)d_in[0];
    const float* flow = (const float*)d_in[1];
    float* out = (float*)d_out;

    // grid: x 4, y 20, z = 16 z-tiles x B2 = 32 -> 2560 blocks
    //     = 5 exact residency rounds at 2 blocks/CU.
    dim3 grid(W_ / XT, H_ / YT, (D_ / ZT) * B_);
    warp3d_tile<<<grid, NTHREADS, 0, stream>>>(src, flow, out);
}